// Round 2
// baseline (1887.240 us; speedup 1.0000x reference)
//
#include <hip/hip_runtime.h>
#include <hip/hip_bf16.h>

// MoE layer: T=16384 tokens, D=1024, F=4096, E=16 experts, top-2, capacity 2560.
// Strategy: bf16 MFMA GEMMs (m97 structure + LDS XOR swizzle), fused epilogues.

#define T_TOK 16384
#define DDIM  1024
#define FDIM  4096
#define NEXP  16
#define TOPK  2
#define CAP   2560              // ceil(2*16384/16 * 1.25)
#define TK    (T_TOK*TOPK)      // 32768

typedef float  floatx4 __attribute__((ext_vector_type(4)));
typedef __bf16 bf16x8  __attribute__((ext_vector_type(8)));

__device__ __forceinline__ unsigned short f2b(float f) {
  union { float f; unsigned int u; } v; v.f = f;
  unsigned int r = (v.u + 0x7FFFu + ((v.u >> 16) & 1u)) >> 16;  // RNE
  return (unsigned short)r;
}

// jax.nn.gelu default (approximate=True, tanh form); tanh via exp.
__device__ __forceinline__ float gelu_tanh(float x) {
  float u = 1.5957691216057308f * (x + 0.044715f * x * x * x); // 2*sqrt(2/pi)*(x+c x^3)
  float eu = __expf(u);
  float t = 1.0f - 2.0f / (eu + 1.0f);
  return 0.5f * x * (1.0f + t);
}

// ---------------- gating: one wave per token ----------------
__global__ void gating_kernel(const float* __restrict__ x, const float* __restrict__ gw,
                              int* __restrict__ topi, float* __restrict__ topv) {
  int gid  = blockIdx.x * blockDim.x + threadIdx.x;
  int tok  = gid >> 6;
  int lane = gid & 63;
  const float* xr = x + (size_t)tok * DDIM;
  float acc[NEXP];
#pragma unroll
  for (int e = 0; e < NEXP; ++e) acc[e] = 0.f;
  for (int j = 0; j < DDIM / 64; ++j) {
    int d = j * 64 + lane;
    float xv = xr[d];
    const float4* g4 = (const float4*)(gw + (size_t)d * NEXP);
    float gv[NEXP];
    *(float4*)&gv[0]  = g4[0];
    *(float4*)&gv[4]  = g4[1];
    *(float4*)&gv[8]  = g4[2];
    *(float4*)&gv[12] = g4[3];
#pragma unroll
    for (int e = 0; e < NEXP; ++e) acc[e] += xv * gv[e];
  }
#pragma unroll
  for (int s = 32; s > 0; s >>= 1) {
#pragma unroll
    for (int e = 0; e < NEXP; ++e) acc[e] += __shfl_xor(acc[e], s, 64);
  }
  if (lane == 0) {
    int i1 = 0; float v1 = acc[0];
#pragma unroll
    for (int e = 1; e < NEXP; ++e) if (acc[e] > v1) { v1 = acc[e]; i1 = e; }
    int i2 = -1; float v2 = -1e30f;
#pragma unroll
    for (int e = 0; e < NEXP; ++e) if (e != i1 && acc[e] > v2) { v2 = acc[e]; i2 = e; }
    float r = __expf(v2 - v1);
    float g1v = 1.0f / (1.0f + r);
    topi[2 * tok] = i1;  topi[2 * tok + 1] = i2;
    topv[2 * tok] = g1v; topv[2 * tok + 1] = 1.0f - g1v;
  }
}

// ---------------- scan: token-major per-expert positions (single block, 512 thr) ----------------
__global__ void scan_kernel(const int* __restrict__ topi, const float* __restrict__ topv,
                            int* __restrict__ slot, int* __restrict__ cnt,
                            int* __restrict__ stok, float* __restrict__ sgate) {
  __shared__ int lcnt[512][17];      // stride 17 ints: bank-conflict-free
  const int PER = TK / 512;          // 64
  int tid = threadIdx.x;
  int base = tid * PER;
  int c[NEXP];
#pragma unroll
  for (int e = 0; e < NEXP; ++e) c[e] = 0;
  for (int i = 0; i < PER; i += 4) {
    int4 v = *(const int4*)(topi + base + i);
#pragma unroll
    for (int e = 0; e < NEXP; ++e)
      c[e] += (v.x == e) + (v.y == e) + (v.z == e) + (v.w == e);
  }
#pragma unroll
  for (int e = 0; e < NEXP; ++e) lcnt[tid][e] = c[e];
  __syncthreads();
  if (tid < NEXP) {
    int run = 0;
    for (int j = 0; j < 512; ++j) { int t = lcnt[j][tid]; lcnt[j][tid] = run; run += t; }
    cnt[tid] = run < CAP ? run : CAP;
  }
  __syncthreads();
#pragma unroll
  for (int e = 0; e < NEXP; ++e) c[e] = lcnt[tid][e];
  for (int i = 0; i < PER; ++i) {
    int ev = topi[base + i];
    int p = 0;
#pragma unroll
    for (int e = 0; e < NEXP; ++e) { p += (ev == e) ? c[e] : 0; c[e] += (ev == e); }
    int s = (p < CAP) ? ev * CAP + p : -1;
    slot[base + i] = s;
    if (s >= 0) { stok[s] = (base + i) >> 1; sgate[s] = topv[base + i]; }
  }
}

// ---------------- scatter x -> xe (bf16) ----------------
__global__ void scatter_kernel(const float* __restrict__ x, const int* __restrict__ slot,
                               unsigned short* __restrict__ xe) {
  int i = blockIdx.x;
  int s = slot[i];
  if (s < 0) return;
  const float* src = x + (size_t)(i >> 1) * DDIM;
  unsigned short* dst = xe + (size_t)s * DDIM;
  int lane = threadIdx.x;
#pragma unroll
  for (int j = 0; j < 4; ++j) {
    int idx = j * 256 + lane * 4;
    float4 v = *(const float4*)(src + idx);
    ushort4 o;
    o.x = f2b(v.x); o.y = f2b(v.y); o.z = f2b(v.z); o.w = f2b(v.w);
    *(ushort4*)(dst + idx) = o;
  }
}

// ---------------- transpose+convert: src fp32 [e][R][Cc] -> dst bf16 [e][Cc][R] ----------------
// fp32 32x32 LDS tiles (4 r-tiles per block); write phase hits the b128 LDS
// minimum, read phase is 4-way scalar (2x min) -- far better than the 8-way
// ushort layout it replaces.
__global__ void transpose_kernel(const float* __restrict__ src, unsigned short* __restrict__ dst,
                                 int R, int Cc) {
  __shared__ __align__(16) float tile[32][36];   // stride 36 floats = 144 B (16B aligned)
  int e = blockIdx.z;
  const float* S = src + (size_t)e * R * Cc;
  unsigned short* Dp = dst + (size_t)e * R * Cc;
  int c0 = blockIdx.x * 32;
  int r0 = blockIdx.y * 128;
  int tr  = threadIdx.x >> 3;        // 0..31
  int tc4 = (threadIdx.x & 7) * 4;   // 0..28
  int oc  = threadIdx.x >> 3;        // 0..31 output row (c-dim)
  int or4 = (threadIdx.x & 7) * 4;   // 0..28 output col chunk (r-dim)
#pragma unroll
  for (int k = 0; k < 4; ++k) {
    int rb = r0 + k * 32;
    float4 v = *(const float4*)(S + (size_t)(rb + tr) * Cc + c0 + tc4);
    *(float4*)&tile[tr][tc4] = v;
    __syncthreads();
    ushort4 o;
    o.x = f2b(tile[or4 + 0][oc]);
    o.y = f2b(tile[or4 + 1][oc]);
    o.z = f2b(tile[or4 + 2][oc]);
    o.w = f2b(tile[or4 + 3][oc]);
    *(ushort4*)(Dp + (size_t)(c0 + oc) * R + rb + or4) = o;
    __syncthreads();
  }
}

// ---------------- MFMA GEMM (m97 structure + XOR swizzle), 128x128 tile, BK=32 ----------------
__device__ __forceinline__ void glds16(const void* g, void* l) {
  __builtin_amdgcn_global_load_lds((const __attribute__((address_space(1))) void*)g,
                                   (__attribute__((address_space(3))) void*)l, 16, 0, 0);
}

// LDS swizzle: 16B chunk of k-window `kc` for tile-row r lives at slot (kc + (r>>1)) & 3.
// Staging lane i (slot s=i&3, row r=i>>2 within its 16-row group) therefore fetches
// global chunk ((s - (r>>1)) & 3); reads un-swizzle in the address. Every b128
// fragment read then hits each bank exactly 2-way (free per m136).

// MODE 0: h = gelu(A@B^T + b1) stored bf16.  MODE 1: out[tok] += gate * (A@B^T + b2), atomic.
template<int MODE>
__global__ __launch_bounds__(256) void moe_gemm(
    const unsigned short* __restrict__ A,   // [E][C][Kd] bf16
    const unsigned short* __restrict__ Bt,  // [E][Nd][Kd] bf16
    const float* __restrict__ bias,         // [E][Nd]
    unsigned short* __restrict__ Hout,      // MODE0
    float* __restrict__ Out,                // MODE1
    const int* __restrict__ cnt,
    const int* __restrict__ stok,
    const float* __restrict__ sgate,
    int Kd, int Nd)
{
  __shared__ __align__(16) char smem[16384];   // A tile 8KB | B tile 8KB
  __shared__ int   s_tok[128];
  __shared__ float s_gate[128];

  int e = blockIdx.z;
  int ccnt = cnt[e];
  int row0 = blockIdx.y * 128;
  if (row0 >= ccnt) return;                    // per-expert early exit (block-uniform)
  int n0 = blockIdx.x * 128;

  int tid  = threadIdx.x;
  int wave = tid >> 6;
  int lane = tid & 63;
  int quad = lane >> 4;
  int l16  = lane & 15;
  int wm = wave & 1, wn = wave >> 1;

  const unsigned short* Ae = A  + (size_t)e * CAP * Kd;
  const unsigned short* Be = Bt + (size_t)e * Nd  * Kd;

  int arow = row0 + wave * 32 + (lane >> 2);
  int brow = n0   + wave * 32 + (lane >> 2);
  int aswz = ((lane & 3) - ((arow >> 1) & 3)) & 3;   // chunk this lane fetches
  int bswz = ((lane & 3) - ((brow >> 1) & 3)) & 3;
  const char* ga = (const char*)(Ae + (size_t)arow * Kd) + aswz * 16;
  const char* gb = (const char*)(Be + (size_t)brow * Kd) + bswz * 16;
  size_t rstep = (size_t)16 * Kd * 2;          // +16 rows (bytes); (r+16)>>1 & 3 unchanged
  char* la = smem + wave * 2048;
  char* lb = smem + 8192 + wave * 2048;

  floatx4 acc[4][4];
#pragma unroll
  for (int i = 0; i < 4; ++i)
#pragma unroll
    for (int j = 0; j < 4; ++j) acc[i][j] = (floatx4){0.f, 0.f, 0.f, 0.f};

  int ksteps = Kd >> 5;
  for (int ks = 0; ks < ksteps; ++ks) {
    glds16(ga, la);
    glds16(ga + rstep, la + 1024);
    glds16(gb, lb);
    glds16(gb + rstep, lb + 1024);
    ga += 64; gb += 64;
    __syncthreads();
    bf16x8 af[4], bfr[4];
#pragma unroll
    for (int i = 0; i < 4; ++i) {
      int ri = wm * 64 + i * 16 + l16;
      af[i] = *(const bf16x8*)(smem + ri * 64 + ((quad + (ri >> 1)) & 3) * 16);
    }
#pragma unroll
    for (int j = 0; j < 4; ++j) {
      int rj = wn * 64 + j * 16 + l16;
      bfr[j] = *(const bf16x8*)(smem + 8192 + rj * 64 + ((quad + (rj >> 1)) & 3) * 16);
    }
#pragma unroll
    for (int i = 0; i < 4; ++i)
#pragma unroll
      for (int j = 0; j < 4; ++j)
        acc[i][j] = __builtin_amdgcn_mfma_f32_16x16x32_bf16(af[i], bfr[j], acc[i][j], 0, 0, 0);
    __syncthreads();
  }

  if (MODE == 1) {
    if (tid < 128) {
      int r = row0 + tid;
      int ok = r < ccnt;
      s_tok[tid]  = ok ? stok[e * CAP + r]  : -1;
      s_gate[tid] = ok ? sgate[e * CAP + r] : 0.f;
    }
    __syncthreads();
  }

#pragma unroll
  for (int i = 0; i < 4; ++i) {
    int rbase = wm * 64 + i * 16 + quad * 4;
#pragma unroll
    for (int j = 0; j < 4; ++j) {
      int col = n0 + wn * 64 + j * 16 + l16;
      float bv = bias[(size_t)e * Nd + col];
#pragma unroll
      for (int r = 0; r < 4; ++r) {
        int rl = rbase + r;
        int rg = row0 + rl;
        float v = acc[i][j][r] + bv;
        if (MODE == 0) {
          if (rg < ccnt)
            Hout[((size_t)e * CAP + rg) * Nd + col] = f2b(gelu_tanh(v));
        } else {
          int t = s_tok[rl];
          if (t >= 0)
            atomicAdd(Out + (size_t)t * Nd + col, s_gate[rl] * v);
        }
      }
    }
  }
}

extern "C" void kernel_launch(void* const* d_in, const int* in_sizes, int n_in,
                              void* d_out, int out_size, void* d_ws, size_t ws_size,
                              hipStream_t stream) {
  const float* x  = (const float*)d_in[0];
  const float* gw = (const float*)d_in[1];
  const float* w1 = (const float*)d_in[2];
  const float* b1 = (const float*)d_in[3];
  const float* w2 = (const float*)d_in[4];
  const float* b2 = (const float*)d_in[5];
  float* out = (float*)d_out;

  char* ws = (char*)d_ws;
  size_t off = 0;
  auto alloc = [&](size_t bytes) -> void* {
    void* p = ws + off;
    off = (off + bytes + 255) & ~(size_t)255;
    return p;
  };
  int*   topi  = (int*)  alloc((size_t)TK * 4);
  float* topv  = (float*)alloc((size_t)TK * 4);
  int*   slot  = (int*)  alloc((size_t)TK * 4);
  int*   cnt   = (int*)  alloc(256);
  int*   stok  = (int*)  alloc((size_t)NEXP * CAP * 4);
  float* sgate = (float*)alloc((size_t)NEXP * CAP * 4);
  unsigned short* xe  = (unsigned short*)alloc((size_t)NEXP * CAP  * DDIM * 2); // 84 MB
  unsigned short* w1t = (unsigned short*)alloc((size_t)NEXP * FDIM * DDIM * 2); // 134 MB [e][f][d]
  unsigned short* w2t = (unsigned short*)alloc((size_t)NEXP * DDIM * FDIM * 2); // 134 MB [e][d][f]
  unsigned short* h   = (unsigned short*)alloc((size_t)NEXP * CAP  * FDIM * 2); // 336 MB
  (void)ws_size; (void)in_sizes; (void)n_in; (void)out_size;

  hipMemsetAsync(d_out, 0, (size_t)T_TOK * DDIM * 4, stream);
  hipLaunchKernelGGL(gating_kernel, dim3(T_TOK / 4), dim3(256), 0, stream, x, gw, topi, topv);
  hipLaunchKernelGGL(scan_kernel, dim3(1), dim3(512), 0, stream, topi, topv, slot, cnt, stok, sgate);
  hipLaunchKernelGGL(scatter_kernel, dim3(TK), dim3(64), 0, stream, x, slot, xe);
  hipLaunchKernelGGL(transpose_kernel, dim3(FDIM / 32, DDIM / 128, NEXP), dim3(256), 0, stream,
                     w1, w1t, DDIM, FDIM);
  hipLaunchKernelGGL(transpose_kernel, dim3(DDIM / 32, FDIM / 128, NEXP), dim3(256), 0, stream,
                     w2, w2t, FDIM, DDIM);
  hipLaunchKernelGGL((moe_gemm<0>), dim3(FDIM / 128, CAP / 128, NEXP), dim3(256), 0, stream,
                     xe, w1t, b1, h, (float*)nullptr, cnt, (int*)nullptr, (float*)nullptr,
                     DDIM, FDIM);
  hipLaunchKernelGGL((moe_gemm<1>), dim3(DDIM / 128, CAP / 128, NEXP), dim3(256), 0, stream,
                     h, w2t, b2, (unsigned short*)nullptr, out, cnt, stok, sgate,
                     FDIM, DDIM);
}

// Round 3
// 1635.784 us; speedup vs baseline: 1.1537x; 1.1537x over previous
//
#include <hip/hip_runtime.h>
#include <hip/hip_bf16.h>

// MoE layer: T=16384 tokens, D=1024, F=4096, E=16 experts, top-2, capacity 2560.
// bf16 MFMA GEMMs (m97 structure + LDS XOR swizzle + L2 panel swizzle),
// plain-store ye + separate combine (no atomics).

#define T_TOK 16384
#define DDIM  1024
#define FDIM  4096
#define NEXP  16
#define TOPK  2
#define CAP   2560              // ceil(2*16384/16 * 1.25)
#define TK    (T_TOK*TOPK)      // 32768

typedef float  floatx4 __attribute__((ext_vector_type(4)));
typedef __bf16 bf16x8  __attribute__((ext_vector_type(8)));

__device__ __forceinline__ unsigned short f2b(float f) {
  union { float f; unsigned int u; } v; v.f = f;
  unsigned int r = (v.u + 0x7FFFu + ((v.u >> 16) & 1u)) >> 16;  // RNE
  return (unsigned short)r;
}

// jax.nn.gelu default (approximate=True, tanh form); tanh via exp.
__device__ __forceinline__ float gelu_tanh(float x) {
  float u = 1.5957691216057308f * (x + 0.044715f * x * x * x);
  float eu = __expf(u);
  float t = 1.0f - 2.0f / (eu + 1.0f);
  return 0.5f * x * (1.0f + t);
}

// ---------------- gating: one wave per token ----------------
__global__ void gating_kernel(const float* __restrict__ x, const float* __restrict__ gw,
                              int* __restrict__ topi, float* __restrict__ topv) {
  int gid  = blockIdx.x * blockDim.x + threadIdx.x;
  int tok  = gid >> 6;
  int lane = gid & 63;
  const float* xr = x + (size_t)tok * DDIM;
  float acc[NEXP];
#pragma unroll
  for (int e = 0; e < NEXP; ++e) acc[e] = 0.f;
  for (int j = 0; j < DDIM / 64; ++j) {
    int d = j * 64 + lane;
    float xv = xr[d];
    const float4* g4 = (const float4*)(gw + (size_t)d * NEXP);
    float gv[NEXP];
    *(float4*)&gv[0]  = g4[0];
    *(float4*)&gv[4]  = g4[1];
    *(float4*)&gv[8]  = g4[2];
    *(float4*)&gv[12] = g4[3];
#pragma unroll
    for (int e = 0; e < NEXP; ++e) acc[e] += xv * gv[e];
  }
#pragma unroll
  for (int s = 32; s > 0; s >>= 1) {
#pragma unroll
    for (int e = 0; e < NEXP; ++e) acc[e] += __shfl_xor(acc[e], s, 64);
  }
  if (lane == 0) {
    int i1 = 0; float v1 = acc[0];
#pragma unroll
    for (int e = 1; e < NEXP; ++e) if (acc[e] > v1) { v1 = acc[e]; i1 = e; }
    int i2 = -1; float v2 = -1e30f;
#pragma unroll
    for (int e = 0; e < NEXP; ++e) if (e != i1 && acc[e] > v2) { v2 = acc[e]; i2 = e; }
    float r = __expf(v2 - v1);
    float g1v = 1.0f / (1.0f + r);
    topi[2 * tok] = i1;  topi[2 * tok + 1] = i2;
    topv[2 * tok] = g1v; topv[2 * tok + 1] = 1.0f - g1v;
  }
}

// ---------------- scan: token-major per-expert positions (single block, 512 thr) ----------------
__global__ void scan_kernel(const int* __restrict__ topi,
                            int* __restrict__ slot, int* __restrict__ cnt) {
  __shared__ int lcnt[512][17];      // stride 17 ints: conflict-free
  const int PER = TK / 512;          // 64
  int tid = threadIdx.x;
  int base = tid * PER;
  int c[NEXP];
#pragma unroll
  for (int e = 0; e < NEXP; ++e) c[e] = 0;
  for (int i = 0; i < PER; i += 4) {
    int4 v = *(const int4*)(topi + base + i);
#pragma unroll
    for (int e = 0; e < NEXP; ++e)
      c[e] += (v.x == e) + (v.y == e) + (v.z == e) + (v.w == e);
  }
#pragma unroll
  for (int e = 0; e < NEXP; ++e) lcnt[tid][e] = c[e];
  __syncthreads();
  if (tid < NEXP) {
    int run = 0;
    for (int j = 0; j < 512; ++j) { int t = lcnt[j][tid]; lcnt[j][tid] = run; run += t; }
    cnt[tid] = run < CAP ? run : CAP;
  }
  __syncthreads();
#pragma unroll
  for (int e = 0; e < NEXP; ++e) c[e] = lcnt[tid][e];
  for (int i = 0; i < PER; ++i) {
    int ev = topi[base + i];
    int p = 0;
#pragma unroll
    for (int e = 0; e < NEXP; ++e) { p += (ev == e) ? c[e] : 0; c[e] += (ev == e); }
    slot[base + i] = (p < CAP) ? ev * CAP + p : -1;
  }
}

// ---------------- scatter x -> xe (bf16); 4 slots per 256-thread block ----------------
__global__ void scatter_kernel(const float* __restrict__ x, const int* __restrict__ slot,
                               unsigned short* __restrict__ xe) {
  int i = blockIdx.x * 4 + (threadIdx.x >> 6);
  int s = slot[i];
  if (s < 0) return;
  const float* src = x + (size_t)(i >> 1) * DDIM;
  unsigned short* dst = xe + (size_t)s * DDIM;
  int lane = threadIdx.x & 63;
#pragma unroll
  for (int j = 0; j < 4; ++j) {
    int idx = j * 256 + lane * 4;
    float4 v = *(const float4*)(src + idx);
    ushort4 o;
    o.x = f2b(v.x); o.y = f2b(v.y); o.z = f2b(v.z); o.w = f2b(v.w);
    *(ushort4*)(dst + idx) = o;
  }
}

// ---------------- transpose+convert: fp32 [e][R][Cc] -> bf16 [e][Cc][R] ----------------
// 64(c) x 64(r) tiles; fp32 LDS [64][65]; output segments are 128 B contiguous.
__global__ void transpose_kernel(const float* __restrict__ src, unsigned short* __restrict__ dst,
                                 int R, int Cc) {
  __shared__ __align__(16) float tile[64][65];
  int e = blockIdx.z;
  const float* S = src + (size_t)e * R * Cc;
  unsigned short* Dp = dst + (size_t)e * R * Cc;
  int c0 = blockIdx.x * 64;
  int r0 = blockIdx.y * 64;
  int tr  = threadIdx.x >> 4;        // 0..15
  int tc4 = (threadIdx.x & 15) * 4;  // 0..60
#pragma unroll
  for (int p = 0; p < 4; ++p) {
    int r = p * 16 + tr;
    float4 v = *(const float4*)(S + (size_t)(r0 + r) * Cc + c0 + tc4);
    *(float4*)&tile[r][tc4] = v;
  }
  __syncthreads();
#pragma unroll
  for (int p = 0; p < 4; ++p) {
    int oc = p * 16 + tr;            // output row (c-dim)
    ushort4 o;
    o.x = f2b(tile[tc4 + 0][oc]);
    o.y = f2b(tile[tc4 + 1][oc]);
    o.z = f2b(tile[tc4 + 2][oc]);
    o.w = f2b(tile[tc4 + 3][oc]);
    *(ushort4*)(Dp + (size_t)(c0 + oc) * R + r0 + tc4) = o;
  }
}

// ---------------- MFMA GEMM (m97 structure + XOR swizzle), 128x128 tile, BK=32 ----------------
__device__ __forceinline__ void glds16(const void* g, void* l) {
  __builtin_amdgcn_global_load_lds((const __attribute__((address_space(1))) void*)g,
                                   (__attribute__((address_space(3))) void*)l, 16, 0, 0);
}

// MODE 0: h = gelu(A@B^T + b1) stored bf16.
// MODE 1: ye = A@B^T + b2 stored fp32 (plain coalesced stores; combine applies gates).
// SWZ  1: within expert, order blocks as n-panels of 2 with full m-sweep inner
//         (keeps A-panel hot in per-XCD L2 while streaming B once per panel).
template<int MODE, int SWZ>
__global__ __launch_bounds__(256) void moe_gemm(
    const unsigned short* __restrict__ A,   // [E][C][Kd] bf16
    const unsigned short* __restrict__ Bt,  // [E][Nd][Kd] bf16
    const float* __restrict__ bias,         // [E][Nd]
    unsigned short* __restrict__ Hout,      // MODE0
    float* __restrict__ Ye,                 // MODE1
    const int* __restrict__ cnt,
    int Kd, int Nd, int nbx, int nby)
{
  __shared__ __align__(16) char smem[16384];   // A tile 8KB | B tile 8KB

  int e = blockIdx.z;
  int ccnt = cnt[e];
  int lin = blockIdx.x;
  int bx, by;
  if (SWZ) {
    int p = lin / (nby * 2);
    int r = lin - p * (nby * 2);
    by = r >> 1;
    bx = p * 2 + (r & 1);
  } else {
    bx = lin % nbx;
    by = lin / nbx;
  }
  int row0 = by * 128;
  if (row0 >= ccnt) return;                    // per-expert early exit
  int n0 = bx * 128;

  int tid  = threadIdx.x;
  int wave = tid >> 6;
  int lane = tid & 63;
  int quad = lane >> 4;
  int l16  = lane & 15;
  int wm = wave & 1, wn = wave >> 1;

  const unsigned short* Ae = A  + (size_t)e * CAP * Kd;
  const unsigned short* Be = Bt + (size_t)e * Nd  * Kd;

  int arow = row0 + wave * 32 + (lane >> 2);
  int brow = n0   + wave * 32 + (lane >> 2);
  int aswz = ((lane & 3) - ((arow >> 1) & 3)) & 3;   // XOR-swizzled chunk fetch
  int bswz = ((lane & 3) - ((brow >> 1) & 3)) & 3;
  const char* ga = (const char*)(Ae + (size_t)arow * Kd) + aswz * 16;
  const char* gb = (const char*)(Be + (size_t)brow * Kd) + bswz * 16;
  size_t rstep = (size_t)16 * Kd * 2;
  char* la = smem + wave * 2048;
  char* lb = smem + 8192 + wave * 2048;

  floatx4 acc[4][4];
#pragma unroll
  for (int i = 0; i < 4; ++i)
#pragma unroll
    for (int j = 0; j < 4; ++j) acc[i][j] = (floatx4){0.f, 0.f, 0.f, 0.f};

  int ksteps = Kd >> 5;
  for (int ks = 0; ks < ksteps; ++ks) {
    glds16(ga, la);
    glds16(ga + rstep, la + 1024);
    glds16(gb, lb);
    glds16(gb + rstep, lb + 1024);
    ga += 64; gb += 64;
    __syncthreads();
    bf16x8 af[4], bfr[4];
#pragma unroll
    for (int i = 0; i < 4; ++i) {
      int ri = wm * 64 + i * 16 + l16;
      af[i] = *(const bf16x8*)(smem + ri * 64 + ((quad + (ri >> 1)) & 3) * 16);
    }
#pragma unroll
    for (int j = 0; j < 4; ++j) {
      int rj = wn * 64 + j * 16 + l16;
      bfr[j] = *(const bf16x8*)(smem + 8192 + rj * 64 + ((quad + (rj >> 1)) & 3) * 16);
    }
#pragma unroll
    for (int i = 0; i < 4; ++i)
#pragma unroll
      for (int j = 0; j < 4; ++j)
        acc[i][j] = __builtin_amdgcn_mfma_f32_16x16x32_bf16(af[i], bfr[j], acc[i][j], 0, 0, 0);
    __syncthreads();
  }

#pragma unroll
  for (int i = 0; i < 4; ++i) {
    int rbase = wm * 64 + i * 16 + quad * 4;
#pragma unroll
    for (int j = 0; j < 4; ++j) {
      int col = n0 + wn * 64 + j * 16 + l16;
      float bv = bias[(size_t)e * Nd + col];
#pragma unroll
      for (int r = 0; r < 4; ++r) {
        int rg = row0 + rbase + r;
        float v = acc[i][j][r] + bv;
        if (MODE == 0)
          Hout[((size_t)e * CAP + rg) * Nd + col] = f2b(gelu_tanh(v));
        else
          Ye[((size_t)e * CAP + rg) * Nd + col] = v;
      }
    }
  }
}

// ---------------- combine: out[t] = sum_k gate_k * ye[slot_k] ----------------
__global__ void combine_kernel(const float* __restrict__ ye, const int* __restrict__ slot,
                               const float* __restrict__ topv, float* __restrict__ out) {
  int t = blockIdx.x * 4 + (threadIdx.x >> 6);
  int lane = threadIdx.x & 63;
  int s0 = slot[2 * t], s1 = slot[2 * t + 1];
  float g0 = topv[2 * t], g1 = topv[2 * t + 1];
  const float* r0 = ye + (size_t)(s0 < 0 ? 0 : s0) * DDIM;
  const float* r1 = ye + (size_t)(s1 < 0 ? 0 : s1) * DDIM;
  float* o = out + (size_t)t * DDIM;
#pragma unroll
  for (int j = 0; j < 4; ++j) {
    int idx = j * 256 + lane * 4;
    float4 a = (s0 >= 0) ? *(const float4*)(r0 + idx) : (float4){0, 0, 0, 0};
    float4 b = (s1 >= 0) ? *(const float4*)(r1 + idx) : (float4){0, 0, 0, 0};
    float4 w;
    w.x = g0 * a.x + g1 * b.x;
    w.y = g0 * a.y + g1 * b.y;
    w.z = g0 * a.z + g1 * b.z;
    w.w = g0 * a.w + g1 * b.w;
    *(float4*)(o + idx) = w;
  }
}

extern "C" void kernel_launch(void* const* d_in, const int* in_sizes, int n_in,
                              void* d_out, int out_size, void* d_ws, size_t ws_size,
                              hipStream_t stream) {
  const float* x  = (const float*)d_in[0];
  const float* gw = (const float*)d_in[1];
  const float* w1 = (const float*)d_in[2];
  const float* b1 = (const float*)d_in[3];
  const float* w2 = (const float*)d_in[4];
  const float* b2 = (const float*)d_in[5];
  float* out = (float*)d_out;

  char* ws = (char*)d_ws;
  size_t off = 0;
  auto alloc = [&](size_t bytes) -> void* {
    void* p = ws + off;
    off = (off + bytes + 255) & ~(size_t)255;
    return p;
  };
  int*   topi  = (int*)  alloc((size_t)TK * 4);
  float* topv  = (float*)alloc((size_t)TK * 4);
  int*   slot  = (int*)  alloc((size_t)TK * 4);
  int*   cnt   = (int*)  alloc(256);
  unsigned short* xe  = (unsigned short*)alloc((size_t)NEXP * CAP  * DDIM * 2); // 84 MB
  unsigned short* w1t = (unsigned short*)alloc((size_t)NEXP * FDIM * DDIM * 2); // 134 MB
  unsigned short* w2t = (unsigned short*)alloc((size_t)NEXP * DDIM * FDIM * 2); // 134 MB
  unsigned short* h   = (unsigned short*)alloc((size_t)NEXP * CAP  * FDIM * 2); // 336 MB
  // ye (168 MB fp32) aliases xe+w1t (218 MB): both dead once GEMM1 completes.
  float* ye = (float*)xe;
  (void)ws_size; (void)in_sizes; (void)n_in; (void)out_size;

  hipLaunchKernelGGL(gating_kernel, dim3(T_TOK / 4), dim3(256), 0, stream, x, gw, topi, topv);
  hipLaunchKernelGGL(scan_kernel, dim3(1), dim3(512), 0, stream, topi, slot, cnt);
  hipLaunchKernelGGL(scatter_kernel, dim3(TK / 4), dim3(256), 0, stream, x, slot, xe);
  hipLaunchKernelGGL(transpose_kernel, dim3(FDIM / 64, DDIM / 64, NEXP), dim3(256), 0, stream,
                     w1, w1t, DDIM, FDIM);
  hipLaunchKernelGGL(transpose_kernel, dim3(DDIM / 64, FDIM / 64, NEXP), dim3(256), 0, stream,
                     w2, w2t, FDIM, DDIM);
  hipLaunchKernelGGL((moe_gemm<0, 1>), dim3((FDIM / 128) * (CAP / 128), 1, NEXP), dim3(256), 0,
                     stream, xe, w1t, b1, h, (float*)nullptr, cnt,
                     DDIM, FDIM, FDIM / 128, CAP / 128);
  hipLaunchKernelGGL((moe_gemm<1, 0>), dim3((DDIM / 128) * (CAP / 128), 1, NEXP), dim3(256), 0,
                     stream, h, w2t, b2, (unsigned short*)nullptr, ye, cnt,
                     FDIM, DDIM, DDIM / 128, CAP / 128);
  hipLaunchKernelGGL(combine_kernel, dim3(T_TOK / 4), dim3(256), 0, stream, ye, slot, topv, out);
}